// Round 10
// baseline (667.607 us; speedup 1.0000x reference)
//
#include <hip/hip_runtime.h>
#include <math.h>

typedef _Float16 f16x8 __attribute__((ext_vector_type(8)));
typedef float    f32x4 __attribute__((ext_vector_type(4)));

#define B_TOT 2048
#define LSEQ  512
#define LOG2E 1.44269504088896f
#define LN2   0.69314718055995f

#define MFMA16(A, B, C) __builtin_amdgcn_mfma_f32_16x16x32_f16((A), (B), (C), 0, 0, 0)

// ONE WAVE = ONE SAMPLE (v21 structure, register-rescued). No barriers in the
// recurrence; h-exchange is a same-wave LDS round-trip (DS in-order per wave;
// correctness verified on-device in v21). B cols = 16 duplicates of the sample.
//
// Lane (n,q) owns ONE cell: feature fo = 4q + (n&3) + 16*(n>>2). Its 4 gate
// values live in tile 4g+cT (cT=n>>2), reg slot (n&3), its OWN lane. All other
// MFMA outputs are discarded. C operands are a shared ZERO quad; the presum
// p0/p1 (8 VGPRs) is added after extraction -- this is what caps the register
// footprint at ~190 (v21's per-gate C build + launch_bounds cap spilled at 128).
__global__ __launch_bounds__(64)
void lstm_v23_kernel(const int* __restrict__ s,
                     const float* __restrict__ W0, const float* __restrict__ b0,
                     const float* __restrict__ Wi, const float* __restrict__ Wh,
                     const float* __restrict__ bh, const float* __restrict__ Wa,
                     const float* __restrict__ ba, const float* __restrict__ Wp,
                     const float* __restrict__ bp, float* __restrict__ out)
{
    const int lane = threadIdx.x;        // block = 1 wave
    const int n    = lane & 15;
    const int q    = lane >> 4;
    const int slot = n & 3;
    const int cT   = n >> 2;
    const int b    = blockIdx.x;         // sample index
    const int fo   = 4 * q + slot + 16 * cT;   // owned feature/cell

    __shared__ __align__(16) _Float16 HX[64];   // h exchange (single buffer:
    __shared__ _Float16 DB[LSEQ];               //  DS ops in-order per wave)
    __shared__ unsigned char TOK[LSEQ + 4];

    // ---- stage tokens: TOK[u] = s_pad[u] (= s[u-1], TOK[0]=0) ----
    #pragma unroll
    for (int j = 0; j < 8; ++j) {
        int t = lane + 64 * j;
        TOK[t + 1] = (unsigned char)s[b * LSEQ + t];
    }
    if (lane == 0) { TOK[0] = 0; TOK[LSEQ + 1] = 0; TOK[LSEQ + 2] = 0; }

    // ---- p0/p1 for this lane's 4 gate-rows rho = 64g + fo ----
    float p0v[4], p1v[4];
    #pragma unroll
    for (int g = 0; g < 4; ++g) { float bb = bh[64 * g + fo]; p0v[g] = bb; p1v[g] = bb; }
    for (int k = 0; k < 64; ++k) {
        float wb0 = W0[k]      + b0[k];
        float wb1 = W0[64 + k] + b0[k];
        #pragma unroll
        for (int g = 0; g < 4; ++g) {
            float wi = Wi[k * 256 + 64 * g + fo];
            p0v[g] = fmaf(wb0, wi, p0v[g]);
            p1v[g] = fmaf(wb1, wi, p1v[g]);
        }
    }
    #pragma unroll
    for (int g = 0; g < 4; ++g) {
        const float sc = (g == 2) ? (2.0f * LOG2E) : (-LOG2E);
        p0v[g] *= sc; p1v[g] *= sc;
    }

    // ---- A-frags: scaled Wh^T, 16 tiles (128 VGPR, the irreducible core) ----
    f16x8 awh[16][2];
    #pragma unroll
    for (int t = 0; t < 16; ++t) {
        const float sc = ((t >> 2) == 2) ? (2.0f * LOG2E) : (-LOG2E);
        #pragma unroll
        for (int c = 0; c < 2; ++c)
            #pragma unroll
            for (int j = 0; j < 8; ++j)
                awh[t][c][j] = (_Float16)(Wh[(32 * c + 8 * q + j) * 256 + 16 * t + n] * sc);
    }
    // d-GEMM A-frag: row 0 = Wa[:,1]-Wa[:,0]
    f16x8 awd[2];
    #pragma unroll
    for (int c = 0; c < 2; ++c)
        #pragma unroll
        for (int j = 0; j < 8; ++j) {
            int k = 32 * c + 8 * q + j;
            awd[c][j] = (_Float16)((n == 0) ? (Wa[2 * k + 1] - Wa[2 * k]) : 0.0f);
        }
    const float dba = ba[1] - ba[0];

    __syncthreads();   // TOK visible (single wave, prologue only)

    const bool is1 = (slot == 1), is2 = (slot == 2), is3 = (slot == 3);
    const bool t1 = (cT == 1), t2 = (cT == 2), t3 = (cT == 3);
    const f32x4 z4 = {0.f, 0.f, 0.f, 0.f};

    float h1 = 0.f, c1 = 0.f;
    int tokc = 0;        // s_pad[0] = 0

    for (int v = 0; v <= LSEQ; ++v) {
        // publish h^{(v)}: one ds_write_b16; reads wait via lgkmcnt only
        HX[fo] = (_Float16)h1;
        const f16x8 bf0 = *(const f16x8*)&HX[8 * q];        // k = 8q..8q+7
        const f16x8 bf1 = *(const f16x8*)&HX[32 + 8 * q];   // k = 32+8q..+7
        const int tokn = TOK[v + 1];

        // d-logit for t = v-1 (unconditional MFMA; guarded 1-lane write)
        {
            f32x4 dv = MFMA16(awd[0], bf0, z4);
            dv = MFMA16(awd[1], bf1, dv);
            if (v >= 1 && lane == 0) DB[v - 1] = (_Float16)dv[0];
        }

        // gates, g-major, C = 0 (pv added after extraction)
        float gv[4];
        #pragma unroll
        for (int g = 0; g < 4; ++g) {
            f32x4 m0 = MFMA16(awh[4 * g + 0][0], bf0, z4);
            f32x4 m1 = MFMA16(awh[4 * g + 1][0], bf0, z4);
            f32x4 m2 = MFMA16(awh[4 * g + 2][0], bf0, z4);
            f32x4 m3 = MFMA16(awh[4 * g + 3][0], bf0, z4);
            m0 = MFMA16(awh[4 * g + 0][1], bf1, m0);
            m1 = MFMA16(awh[4 * g + 1][1], bf1, m1);
            m2 = MFMA16(awh[4 * g + 2][1], bf1, m2);
            m3 = MFMA16(awh[4 * g + 3][1], bf1, m3);
            // slot-select within each candidate tile, then cT-select
            float s0 = m0[0]; s0 = is1 ? m0[1] : s0; s0 = is2 ? m0[2] : s0; s0 = is3 ? m0[3] : s0;
            float s1 = m1[0]; s1 = is1 ? m1[1] : s1; s1 = is2 ? m1[2] : s1; s1 = is3 ? m1[3] : s1;
            float s2 = m2[0]; s2 = is1 ? m2[1] : s2; s2 = is2 ? m2[2] : s2; s2 = is3 ? m2[3] : s2;
            float s3 = m3[0]; s3 = is1 ? m3[1] : s3; s3 = is2 ? m3[2] : s3; s3 = is3 ? m3[3] : s3;
            float x = s0; x = t1 ? s1 : x; x = t2 ? s2 : x; x = t3 ? s3 : x;
            float pv = tokc ? p1v[g] : p0v[g];
            gv[g] = x + pv;
        }
        tokc = tokn;

        // activation: 5 exp2 + 2 rcp (single cell)
        {
            float ei = __builtin_amdgcn_exp2f(gv[0]);               // e^{-i}
            float ef = __builtin_amdgcn_exp2f(gv[1]);               // e^{-f}
            float eg = __builtin_amdgcn_exp2f(gv[2]);               // e^{2g}
            float eo = __builtin_amdgcn_exp2f(gv[3]);               // e^{-o}
            float P  = (1.0f + ei) * (eg + 1.0f);
            float F  = 1.0f + ef;
            float R2 = __builtin_amdgcn_rcpf(P * F);
            float cn = fmaf(c1 * P, R2, (eg - 1.0f) * F * R2);
            c1 = cn;
            float ec = __builtin_amdgcn_exp2f(fminf(cn * (2.0f * LOG2E), 60.f));
            float Ro = __builtin_amdgcn_rcpf((1.0f + eo) * (ec + 1.0f));
            h1 = (ec - 1.0f) * Ro;
        }
    }

    __syncthreads();   // DB complete (single wave)

    // ---- amp: softplus over 512 steps (dba folded in here), reduce ----
    float aa = 0.f;
    #pragma unroll 2
    for (int j = 0; j < 8; ++j) {
        int t = lane + 64 * j;
        float d = (float)DB[t] + dba;
        float x = TOK[t + 1] ? -d : d;          // sign by actual token s[t]
        float e = __builtin_amdgcn_exp2f(-fabsf(x) * LOG2E);
        aa += fmaxf(x, 0.f) + __builtin_amdgcn_logf(1.0f + e) * LN2;
    }
    // phase from register h^{(513)} (1 feature/lane)
    float ph = h1 * Wp[fo];
    #pragma unroll
    for (int m = 1; m < 64; m <<= 1) {
        aa += __shfl_xor(aa, m, 64);
        ph += __shfl_xor(ph, m, 64);
    }
    if (lane == 0) {
        out[b]         = -0.5f * aa;        // planar real
        out[B_TOT + b] = ph + bp[0];        // planar imag
    }
}

extern "C" void kernel_launch(void* const* d_in, const int* in_sizes, int n_in,
                              void* d_out, int out_size, void* d_ws, size_t ws_size,
                              hipStream_t stream) {
    const int*   s  = (const int*)  d_in[0];
    const float* W0 = (const float*)d_in[1];
    const float* b0 = (const float*)d_in[2];
    const float* Wi = (const float*)d_in[3];
    const float* Wh = (const float*)d_in[4];
    const float* bh = (const float*)d_in[5];
    const float* Wa = (const float*)d_in[6];
    const float* ba = (const float*)d_in[7];
    const float* Wp = (const float*)d_in[8];
    const float* bp = (const float*)d_in[9];
    float* out = (float*)d_out;

    dim3 grid(B_TOT);        // 2048 blocks x 1 wave: 2 waves/SIMD target,
    dim3 block(64);          // zero barriers in the recurrence
    lstm_v23_kernel<<<grid, block, 0, stream>>>(s, W0, b0, Wi, Wh, bh,
                                                Wa, ba, Wp, bp, out);
}

// Round 11
// 263.556 us; speedup vs baseline: 2.5331x; 2.5331x over previous
//
#include <hip/hip_runtime.h>
#include <math.h>

typedef _Float16 f16x8 __attribute__((ext_vector_type(8)));
typedef float    f32x4 __attribute__((ext_vector_type(4)));
typedef float    f32x2 __attribute__((ext_vector_type(2)));
typedef _Float16 f16x2 __attribute__((ext_vector_type(2)));
typedef __fp16   fp16x2 __attribute__((ext_vector_type(2)));

#define B_TOT 2048
#define LSEQ  512
#define NS    8            // samples per block; 256 blocks -> all 256 CUs
#define LOG2E 1.44269504088896f
#define LN2   0.69314718055995f

#define MFMA16(A, B, C) __builtin_amdgcn_mfma_f32_16x16x32_f16((A), (B), (C), 0, 0, 0)

__device__ __forceinline__ unsigned int pkrtz(float a, float b) {
    fp16x2 p = __builtin_amdgcn_cvt_pkrtz(a, b);
    return __builtin_bit_cast(unsigned int, p);
}

__global__ __launch_bounds__(256, 1)
void lstm_v24_kernel(const int* __restrict__ s,
                     const float* __restrict__ W0, const float* __restrict__ b0,
                     const float* __restrict__ Wi, const float* __restrict__ Wh,
                     const float* __restrict__ bh, const float* __restrict__ Wa,
                     const float* __restrict__ ba, const float* __restrict__ Wp,
                     const float* __restrict__ bp, float* __restrict__ out)
{
    const int tid  = threadIdx.x;
    const int w    = tid >> 6;     // wave 0..3: feature block 16w..16w+15 (all 4 gates)
    const int lane = tid & 63;
    const int n    = lane & 15;    // MFMA column; samples duplicated: col n == col n+8
    const int q    = lane >> 4;
    const int ns   = n & 7;        // sample index
    const int hi   = n >> 3;       // row-half: lane n<8 -> acc rows {0,1}, n>=8 -> {2,3}
    const int b0s  = blockIdx.x * NS;

    // h layout: sample sN, chunk c (features 8c..8c+7) = 4 dwords at
    // 4*sN + 64*(c&1) + 128*(c>>1).  Each lane publishes ONE dword (2 features),
    // reads 2x ds_read_b128; cols n/n+8 read the same address (broadcast, free).
    __shared__ __align__(16) unsigned int HhD[2][512];  //  4 KB
    __shared__ unsigned short TOKB[LSEQ + 2];           //  1 KB
    __shared__ unsigned char  SRAW[NS][LSEQ];           //  4 KB
    __shared__ _Float16 DBUF[LSEQ][NS];                 //  8 KB
    __shared__ float PART[32][NS];                      //  1 KB

    // ---- stage tokens (coalesced in t) ----
    for (int i = tid; i < NS * LSEQ; i += 256)
        SRAW[i >> 9][i & 511] = (unsigned char)s[(b0s + (i >> 9)) * LSEQ + (i & 511)];
    __syncthreads();
    for (int u = tid; u <= LSEQ; u += 256) {
        unsigned int mask = 0;
        if (u >= 1) {
            #pragma unroll
            for (int m = 0; m < NS; ++m)
                mask |= ((unsigned int)SRAW[m][u - 1]) << m;
        }
        TOKB[u] = (unsigned short)mask;
    }

    // ---- A-frags: scaled Wh^T (row m = n, full 16 rows) ----
    f16x8 awh[4][2];
    #pragma unroll
    for (int g = 0; g < 4; ++g) {
        const float sc  = (g == 2) ? (2.0f * LOG2E) : (-LOG2E);
        const int   col = 64 * g + 16 * w + n;
        #pragma unroll
        for (int c = 0; c < 2; ++c)
            #pragma unroll
            for (int j = 0; j < 8; ++j)
                awh[g][c][j] = (_Float16)(Wh[(32 * c + 8 * q + j) * 256 + col] * sc);
    }

    // ---- d-GEMM A-frag: row 0 = Wa[:,1]-Wa[:,0] ----
    f16x8 awd[2];
    #pragma unroll
    for (int c = 0; c < 2; ++c)
        #pragma unroll
        for (int j = 0; j < 8; ++j) {
            int k = 32 * c + 8 * q + j;
            awd[c][j] = (_Float16)((n == 0) ? (Wa[2 * k + 1] - Wa[2 * k]) : 0.0f);
        }
    const float dba = ba[1] - ba[0];

    // ---- p0/dp (scaled), full 4 rows per lane (MFMA C operand) ----
    f32x4 p0q[4], dpq[4];
    {
        float a0[4][4], a1[4][4];
        #pragma unroll
        for (int g = 0; g < 4; ++g)
            #pragma unroll
            for (int r = 0; r < 4; ++r) {
                float bb = bh[64 * g + 16 * w + 4 * q + r];
                a0[g][r] = bb; a1[g][r] = bb;
            }
        for (int f = 0; f < 64; ++f) {
            float wb0 = W0[f]      + b0[f];
            float wb1 = W0[64 + f] + b0[f];
            #pragma unroll
            for (int g = 0; g < 4; ++g) {
                const float4 wi4 = *(const float4*)&Wi[f * 256 + 64 * g + 16 * w + 4 * q];
                #pragma unroll
                for (int r = 0; r < 4; ++r) {
                    float wi = (&wi4.x)[r];
                    a0[g][r] = fmaf(wb0, wi, a0[g][r]);
                    a1[g][r] = fmaf(wb1, wi, a1[g][r]);
                }
            }
        }
        #pragma unroll
        for (int g = 0; g < 4; ++g) {
            const float sc = (g == 2) ? (2.0f * LOG2E) : (-LOG2E);
            #pragma unroll
            for (int r = 0; r < 4; ++r) {
                p0q[g][r] = a0[g][r] * sc;
                dpq[g][r] = (a1[g][r] - a0[g][r]) * sc;
            }
        }
    }

    __syncthreads();   // TOKB ready

    // ---- loop-invariant LDS dword addresses ----
    const int wAddr = 4 * ns + 64 * (q >> 1) + 128 * w + 2 * (q & 1) + hi;
    const int rAddr = 4 * ns + 64 * (q & 1) + 128 * (q >> 1);

    // ---- state: 2 cells per lane, packed pair ----
    f32x2 h2 = {0.f, 0.f}, c2 = {0.f, 0.f};
    f32x4 ci[4];
    #pragma unroll
    for (int g = 0; g < 4; ++g) ci[g] = p0q[g];

    const f32x2 one2 = {1.f, 1.f};
    float dpend = 0.0f;      // wave 0's deferred d-result (written one step late)

    #pragma unroll 4
    for (int v = 0; v <= LSEQ; ++v) {
        const int p = v & 1;
        unsigned int* __restrict__ hb = &HhD[p][0];

        // publish h_{v-1}: one ds_write_b32 (head of the serial chain -> first)
        hb[wAddr] = pkrtz(h2[0], h2[1]);
        __syncthreads();

        // B-frags: two ds_read_b128 (cols n / n+8 broadcast same sample)
        uint4 r0 = *(const uint4*)&hb[rAddr];
        uint4 r1 = *(const uint4*)&hb[rAddr + 256];
        const f16x8 bf0 = __builtin_bit_cast(f16x8, r0);
        const f16x8 bf1 = __builtin_bit_cast(f16x8, r1);

        // flush wave0's deferred d-result for t = v-2 (after the reads: DS is
        // in-order per wave, so this b16 write doesn't delay the b128 data)
        if (v >= 2 && w == 0) {
            if (lane < 8) DBUF[v - 2][n] = (_Float16)dpend;
        }

        const unsigned int tokm_next = (v < LSEQ) ? (unsigned int)TOKB[v + 1] : 0u;
        const bool hb2 = (hi != 0);

        // ---- gates GEMM, per-gate pipelined: extract+exp2 of gate g runs
        // under the MFMA issue of gate g+2 (trans overlap MFMA shadow) ----
        f32x4 acc0 = ci[0], acc1 = ci[1], acc2 = ci[2], acc3 = ci[3];
        acc0 = MFMA16(awh[0][0], bf0, acc0);
        acc0 = MFMA16(awh[0][1], bf1, acc0);
        acc1 = MFMA16(awh[1][0], bf0, acc1);
        acc1 = MFMA16(awh[1][1], bf1, acc1);

        f32x2 gi = { hb2 ? acc0[2] : acc0[0], hb2 ? acc0[3] : acc0[1] };
        f32x2 ei = { __builtin_amdgcn_exp2f(gi[0]), __builtin_amdgcn_exp2f(gi[1]) };

        acc2 = MFMA16(awh[2][0], bf0, acc2);
        acc2 = MFMA16(awh[2][1], bf1, acc2);

        f32x2 gf = { hb2 ? acc1[2] : acc1[0], hb2 ? acc1[3] : acc1[1] };
        f32x2 ef = { __builtin_amdgcn_exp2f(gf[0]), __builtin_amdgcn_exp2f(gf[1]) };

        acc3 = MFMA16(awh[3][0], bf0, acc3);
        acc3 = MFMA16(awh[3][1], bf1, acc3);

        f32x2 gg = { hb2 ? acc2[2] : acc2[0], hb2 ? acc2[3] : acc2[1] };
        f32x2 eg = { __builtin_amdgcn_exp2f(gg[0]), __builtin_amdgcn_exp2f(gg[1]) };

        // d-GEMM last (off the gate->extract chain): all waves compute
        // (identical streams, no straggler); only wave 0's result consumed.
        if (v >= 1) {
            f32x4 da = (f32x4){dba, dba, dba, dba};
            da = MFMA16(awd[0], bf0, da);
            da = MFMA16(awd[1], bf1, da);
            dpend = da[0];
        }

        f32x2 go = { hb2 ? acc3[2] : acc3[0], hb2 ? acc3[3] : acc3[1] };
        f32x2 eo = { __builtin_amdgcn_exp2f(go[0]), __builtin_amdgcn_exp2f(go[1]) };

        // C-init for next iter (off-chain; scheduler hides under trans)
        const float sel = (float)((tokm_next >> ns) & 1u);
        const f32x4 sel4 = {sel, sel, sel, sel};
        #pragma unroll
        for (int g = 0; g < 4; ++g)
            ci[g] = dpq[g] * sel4 + p0q[g];

        // ---- act merge (identical algebra to v22) ----
        f32x2 P  = (one2 + ei) * (eg + one2);
        f32x2 F  = one2 + ef;
        f32x2 PF = P * F;
        f32x2 R2 = { __builtin_amdgcn_rcpf(PF[0]), __builtin_amdgcn_rcpf(PF[1]) };
        f32x2 cn = (c2 * P) * R2 + ((eg - one2) * F) * R2;
        c2 = cn;
        f32x2 ar = cn * (f32x2){2.0f * LOG2E, 2.0f * LOG2E};
        ar = (f32x2){ fminf(ar[0], 60.f), fminf(ar[1], 60.f) };
        f32x2 ec = { __builtin_amdgcn_exp2f(ar[0]), __builtin_amdgcn_exp2f(ar[1]) };
        f32x2 dn = (one2 + eo) * (ec + one2);
        f32x2 Ro = { __builtin_amdgcn_rcpf(dn[0]), __builtin_amdgcn_rcpf(dn[1]) };
        h2 = (ec - one2) * Ro;
    }

    // ---- tail: flush wave0's last d (t=511), publish h_512 into buffer 1 ----
    if (w == 0 && lane < 8) DBUF[511][n] = (_Float16)dpend;
    HhD[1][wAddr] = pkrtz(h2[0], h2[1]);
    __syncthreads();

    // ---- amp post-pass: 8 samples x 512 t, 16 t per thread ----
    {
        const int nn = tid & 7;
        const int cp = tid >> 3;             // 0..31
        float a = 0.0f;
        #pragma unroll 4
        for (int k = 0; k < 16; ++k) {
            int t = cp * 16 + k;
            float d = (float)DBUF[t][nn];
            float x = SRAW[nn][t] ? -d : d;
            float e = __builtin_amdgcn_exp2f(-fabsf(x) * LOG2E);
            a += fmaxf(x, 0.0f) + __builtin_amdgcn_logf(1.0f + e) * LN2;
        }
        PART[cp][nn] = a;
    }
    __syncthreads();

    if (tid < 8) {
        float ssum = 0.0f;
        #pragma unroll
        for (int c = 0; c < 32; ++c) ssum += PART[c][tid];
        out[b0s + tid] = -0.5f * ssum;              // planar real
    }

    // ---- phase: wave 0; lane (n,q) covers features 16q..16q+15 of sample ns
    if (w == 0) {
        float ph = 0.0f;
        #pragma unroll
        for (int d = 0; d < 4; ++d) {
            unsigned int ua = HhD[1][4 * ns + 128 * q + d];
            unsigned int ub = HhD[1][4 * ns + 64 + 128 * q + d];
            f16x2 ha = __builtin_bit_cast(f16x2, ua);
            f16x2 hc = __builtin_bit_cast(f16x2, ub);
            ph = fmaf((float)ha[0], Wp[16 * q + 2 * d],
                 fmaf((float)ha[1], Wp[16 * q + 2 * d + 1], ph));
            ph = fmaf((float)hc[0], Wp[16 * q + 8 + 2 * d],
                 fmaf((float)hc[1], Wp[16 * q + 8 + 2 * d + 1], ph));
        }
        ph += __shfl_xor(ph, 16, 64);
        ph += __shfl_xor(ph, 32, 64);
        if (q == 0 && n < 8) out[B_TOT + b0s + n] = ph + bp[0];   // planar imag
    }
}

extern "C" void kernel_launch(void* const* d_in, const int* in_sizes, int n_in,
                              void* d_out, int out_size, void* d_ws, size_t ws_size,
                              hipStream_t stream) {
    const int*   s  = (const int*)  d_in[0];
    const float* W0 = (const float*)d_in[1];
    const float* b0 = (const float*)d_in[2];
    const float* Wi = (const float*)d_in[3];
    const float* Wh = (const float*)d_in[4];
    const float* bh = (const float*)d_in[5];
    const float* Wa = (const float*)d_in[6];
    const float* ba = (const float*)d_in[7];
    const float* Wp = (const float*)d_in[8];
    const float* bp = (const float*)d_in[9];
    float* out = (float*)d_out;

    dim3 grid(B_TOT / NS);   // 256 WGs x 4 waves (v16/v22 topology)
    dim3 block(256);
    lstm_v24_kernel<<<grid, block, 0, stream>>>(s, W0, b0, Wi, Wh, bh,
                                                Wa, ba, Wp, bp, out);
}